// Round 10
// baseline (146.711 us; speedup 1.0000x reference)
//
#include <hip/hip_runtime.h>

// Problem constants (match reference)
constexpr int N = 64, C = 256, H = 64, W = 64, P = 1024;
constexpr int PLANE = H * W;     // 4096 floats = 16 KB
constexpr int GCW   = 8;         // channels per wave-task
constexpr int PPL   = 16;        // points per lane (1024/64)
constexpr int NBUF  = 3;         // wave-private ring of 3 planes

typedef float v4f __attribute__((ext_vector_type(4)));

// DISCRIMINATING EXPERIMENT (rounds 3-9 all land 79-93us regardless of
// pipeline depth / barrier count / occupancy / stream shape):
// hypothesis A = block-wide barrier convoy; B = per-CU DMA-stream cap.
// This kernel removes ALL inter-wave coupling: 1 wave per block, ZERO
// barriers. Each wave owns (n, 8 channels), stages its 16 KB planes into
// wave-PRIVATE LDS (ring-3), synchronized only by its own counted vmcnt;
// single-wave program order makes buffer reuse safe with lgkmcnt drains.
//   A true -> big win (waves never wait on each other).
//   B true -> unchanged ~80us -> structural ceiling, declare roofline.
//
// Task map: XCD x8 = b&7 owns images x8*8..x8*8+7 (input AND output slices
// L2-local per XCD); cg pairs (sub=q&1) adjacent in dispatch so the two 32 B
// halves of each 64 B output line are written co-XCD, near-in-time -> L2
// merges. Lane store granularity 32 B = one HBM sector (no amplification).
__device__ __forceinline__ void stage_plane(const float* __restrict__ src,
                                            float* __restrict__ dst, int lane) {
    #pragma unroll
    for (int j = 0; j < 16; ++j) {   // 16 x (64 lanes x 16 B) = 16 KB
        __builtin_amdgcn_global_load_lds(
            (const __attribute__((address_space(1))) void*)(src + j * 256 + (lane << 2)),
            (__attribute__((address_space(3))) void*)(dst + j * 256),  // uniform base
            16, 0, 0);
    }
}

__global__ __launch_bounds__(64) void progressive_sample_kernel(
    const float* __restrict__ inp,     // [N,C,H,W]
    const float* __restrict__ point,   // [N,P,2] (y,x)
    const float* __restrict__ offset,  // [N,P,2]
    float* __restrict__ out)           // [N,P,C]
{
    __shared__ __align__(16) float buf[NBUF][PLANE];   // 48 KB -> 3 blocks/CU

    const int b    = blockIdx.x;
    const int x8   = b & 7;            // XCD id under b%8 dispatch
    const int q    = b >> 3;           // 0..255 per XCD
    const int sub  = q & 1;            // which half of the 64 B output line
    const int lg   = q >> 1;           // 0..127
    const int n    = (x8 << 3) + (lg >> 4);        // image: 8 per XCD
    const int cg   = ((lg & 15) << 1) + sub;       // 0..31
    const int c0   = cg * GCW;
    const int lane = threadIdx.x;      // 0..63 (one wave)

    const float* src = inp + ((size_t)n * C + c0) * PLANE;

    // --- coord loads for my 16 points (oldest vmem; retire under ctx) ---
    float py[PPL], px[PPL];
    #pragma unroll
    for (int j = 0; j < PPL; ++j) {
        const int p = (j << 6) + lane;
        const float2 pt = ((const float2*)point )[((size_t)n << 10) + p];
        const float2 of = ((const float2*)offset)[((size_t)n << 10) + p];
        py[j] = pt.x + of.x;
        px[j] = pt.y + of.y;
    }

    // --- prologue: planes 0,1 in flight (32 gll outstanding) ---
    stage_plane(src,         buf[0], lane);
    stage_plane(src + PLANE, buf[1], lane);

    // --- ctx once per point; corner offsets collapse to dxy = dx + 64*dy ---
    int   i00[PPL], dxy[PPL];
    float w00[PPL], w01[PPL], w10[PPL], w11[PPL];
    #pragma unroll
    for (int j = 0; j < PPL; ++j) {
        const float y = py[j], x = px[j];
        const float y0f = floorf(y), x0f = floorf(x);
        const float ly = y - y0f, lx = x - x0f;
        const float hy = 1.0f - ly, hx = 1.0f - lx;
        const int y0 = (int)y0f, xi0 = (int)x0f, y1 = y0 + 1, xi1 = xi0 + 1;
        const bool vy0 = (unsigned)y0 < (unsigned)H, vy1 = (unsigned)y1 < (unsigned)H;
        const bool vx0 = (unsigned)xi0 < (unsigned)W, vx1 = (unsigned)xi1 < (unsigned)W;
        const int yc0 = min(max(y0, 0), H - 1), yc1 = min(max(y1, 0), H - 1);
        const int xc0 = min(max(xi0, 0), W - 1), xc1 = min(max(xi1, 0), W - 1);
        i00[j] = yc0 * W + xc0;
        dxy[j] = (xc1 - xc0) | ((yc1 - yc0) << 6);   // bit0 = dx, bit6 = dy
        w00[j] = (vy0 && vx0) ? hy * hx : 0.0f;
        w01[j] = (vy0 && vx1) ? hy * lx : 0.0f;
        w10[j] = (vy1 && vx0) ? ly * hx : 0.0f;
        w11[j] = (vy1 && vx1) ? ly * lx : 0.0f;
    }

    float acc[PPL][GCW];               // statically indexed -> registers

    // --- wave-private pipeline: 8 phases, NO barriers anywhere ---
    // vmcnt ledger (16 gll per plane): top of phase c outstanding = planes
    // {c, c+1} (32) -> wait vmcnt(16) retires plane c; last phase wait 0.
    // stage(c+2) overwrites buf[(c+2)%3] = plane (c-1)'s buffer; my own
    // reads of it were lgkm-drained at end of phase c-1 (single wave).
    #pragma unroll
    for (int c = 0; c < GCW; ++c) {
        if (c < GCW - 1) {
            asm volatile("s_waitcnt vmcnt(16)" ::: "memory");
        } else {
            asm volatile("s_waitcnt vmcnt(0)" ::: "memory");
        }
        __builtin_amdgcn_sched_barrier(0);

        if (c + 2 < GCW)               // issue early: window = full next phase
            stage_plane(src + (size_t)(c + 2) * PLANE, buf[(c + 2) % NBUF], lane);

        const float* __restrict__ bk = buf[c % NBUF];
        #pragma unroll
        for (int j = 0; j < PPL; ++j) {
            const int a00 = i00[j];
            const int a01 = a00 + (dxy[j] & 1);
            const int a10 = a00 + (dxy[j] & ~1);
            const int a11 = a00 + dxy[j];
            acc[j][c] = bk[a00] * w00[j] + bk[a01] * w01[j]
                      + bk[a10] * w10[j] + bk[a11] * w11[j];
        }

        asm volatile("s_waitcnt lgkmcnt(0)" ::: "memory");   // my reads done
        __builtin_amdgcn_sched_barrier(0);
    }

    // --- stores: lane owns 32 B (8 ch) of its point's line; paired task
    //     (sub^1, same XCD, adjacent dispatch) supplies the other 32 B ---
    #pragma unroll
    for (int j = 0; j < PPL; ++j) {
        float* o = out + (((size_t)n << 10) + (j << 6) + lane) * C + c0;
        v4f lo = { acc[j][0], acc[j][1], acc[j][2], acc[j][3] };
        v4f hi = { acc[j][4], acc[j][5], acc[j][6], acc[j][7] };
        *(v4f*)o       = lo;
        *(v4f*)(o + 4) = hi;
    }
}

extern "C" void kernel_launch(void* const* d_in, const int* in_sizes, int n_in,
                              void* d_out, int out_size, void* d_ws, size_t ws_size,
                              hipStream_t stream) {
    const float* inp    = (const float*)d_in[0];
    const float* point  = (const float*)d_in[1];
    const float* offset = (const float*)d_in[2];
    float* out = (float*)d_out;

    progressive_sample_kernel<<<N * (C / GCW), 64, 0, stream>>>(
        inp, point, offset, out);
}

// Round 11
// 113.752 us; speedup vs baseline: 1.2897x; 1.2897x over previous
//
#include <hip/hip_runtime.h>

// Problem constants (match reference)
constexpr int N = 64, C = 256, H = 64, W = 64, P = 1024;
constexpr int PLANE   = H * W;    // 4096 floats = 16 KB
constexpr int GC      = 16;       // channel-planes per block (thread owns a
                                  // point's full 64 B output line)
constexpr int THREADS = 1024;     // 16 waves; 1 float4/thread stages a plane
constexpr int NBUF    = 3;

typedef float v4f __attribute__((ext_vector_type(4)));

// DISCRIMINATOR, take 2 (round 10 was confounded by 3-waves/CU occupancy):
// every ~80us kernel staged via global_load_lds; the 6.29 TB/s copy ceiling
// uses load-to-VGPR + store. This round: identical best shape to round 9
// (32 waves/CU) but staging = reg path with T14 issue-early/write-late:
//   phase k: s_barrier -> issue load(plane k+2)->VGPR -> gather plane k
//            (4x ds_read+FMA) -> ds_write plane k+1 from regs (loaded in
//            phase k-1; compiler emits counted vmcnt before the write)
//            -> lgkmcnt(0).
// Raw s_barrier does NOT drain vmcnt, so the in-flight load survives the
// barrier (unlike __syncthreads). Load->consume window ~1.5 phases (~4000cy)
// >> 900cy HBM latency. Buffer ring: phase k writes buf[(k+1)%3] =
// buf[(k-2)%3], whose readers finished in phase k-2 (barrier-ordered).
//   If global_load_lds was the ~4 TB/s cap -> expect 60-67us.
//   If unchanged -> structural mixed-stream ceiling; declare roofline.
__global__ __launch_bounds__(THREADS, 8) void progressive_sample_kernel(
    const float* __restrict__ inp,     // [N,C,H,W]
    const float* __restrict__ point,   // [N,P,2] (y,x)
    const float* __restrict__ offset,  // [N,P,2]
    float* __restrict__ out)           // [N,P,C]
{
    __shared__ __align__(16) float buf[NBUF][PLANE];   // 48 KB -> 2 blocks/CU
                                                       // (wave-capped)
    const int b  = blockIdx.x;
    const int n  = b >> 4;             // 16 channel-groups per image
    const int gq = b & 15;
    const int t  = threadIdx.x;
    const int c0 = gq * GC;

    const float4* __restrict__ srcv =
        (const float4*)(inp + ((size_t)n * C + c0) * PLANE);

    // --- prologue: coords first (oldest vmem), then planes 0,1 to regs ---
    const float2 pt2 = ((const float2*)point )[((size_t)n << 10) + t];
    const float2 of2 = ((const float2*)offset)[((size_t)n << 10) + t];
    float4 g0t = srcv[t];                      // plane 0
    float4 g[2];
    g[1] = srcv[1024 + t];                     // plane 1 (phase 0 ds-writes g[1])

    // ctx for this thread's point (consumes coords at vmcnt(2); planes fly)
    const float y = pt2.x + of2.x;
    const float x = pt2.y + of2.y;
    const float y0f = floorf(y), x0f = floorf(x);
    const float ly = y - y0f, lx = x - x0f;
    const float hy = 1.0f - ly, hx = 1.0f - lx;
    const int y0 = (int)y0f, xi0 = (int)x0f, y1 = y0 + 1, xi1 = xi0 + 1;
    const bool vy0 = (unsigned)y0 < (unsigned)H, vy1 = (unsigned)y1 < (unsigned)H;
    const bool vx0 = (unsigned)xi0 < (unsigned)W, vx1 = (unsigned)xi1 < (unsigned)W;
    const int yc0 = min(max(y0, 0), H - 1), yc1 = min(max(y1, 0), H - 1);
    const int xc0 = min(max(xi0, 0), W - 1), xc1 = min(max(xi1, 0), W - 1);
    const int i00 = yc0 * W + xc0, i01 = yc0 * W + xc1;
    const int i10 = yc1 * W + xc0, i11 = yc1 * W + xc1;
    const float w00 = (vy0 && vx0) ? hy * hx : 0.0f;
    const float w01 = (vy0 && vx1) ? hy * lx : 0.0f;
    const float w10 = (vy1 && vx0) ? ly * hx : 0.0f;
    const float w11 = (vy1 && vx1) ? ly * lx : 0.0f;

    // plane 0 into buf[0] (compiler waits vmcnt(1): g[1] stays in flight)
    *(float4*)&buf[0][t << 2] = g0t;
    asm volatile("s_waitcnt lgkmcnt(0)" ::: "memory");
    __builtin_amdgcn_sched_barrier(0);

    float acc[GC];                     // statically indexed after unroll

    #pragma unroll
    for (int k = 0; k < GC; ++k) {
        __builtin_amdgcn_s_barrier();  // buf[k%3] ready (writers lgkm-drained);
                                       // buf[(k+1)%3]'s old readers done
        __builtin_amdgcn_sched_barrier(0);

        if (k + 2 < GC)                // T14 issue-early: plane k+2 -> regs
            g[k & 1] = srcv[(k + 2) * 1024 + t];

        const float* __restrict__ bk = &buf[k % 3][0];
        acc[k] = bk[i00] * w00 + bk[i01] * w01
               + bk[i10] * w10 + bk[i11] * w11;

        if (k + 1 < GC)                // write-late: plane k+1 (loaded k-1)
            *(float4*)&buf[(k + 1) % 3][t << 2] = g[(k + 1) & 1];

        asm volatile("s_waitcnt lgkmcnt(0)" ::: "memory");
        __builtin_amdgcn_sched_barrier(0);
    }

    // --- store: thread owns its point's FULL 64 B line (16 ch); this exact
    //     pattern measured WRITE_SIZE == 64 MB in rounds 6/7 ---
    float* o = out + (((size_t)n << 10) + t) * C + c0;
    #pragma unroll
    for (int q = 0; q < 4; ++q) {
        v4f v = { acc[4*q+0], acc[4*q+1], acc[4*q+2], acc[4*q+3] };
        *(v4f*)(o + 4 * q) = v;
    }
}

extern "C" void kernel_launch(void* const* d_in, const int* in_sizes, int n_in,
                              void* d_out, int out_size, void* d_ws, size_t ws_size,
                              hipStream_t stream) {
    const float* inp    = (const float*)d_in[0];
    const float* point  = (const float*)d_in[1];
    const float* offset = (const float*)d_in[2];
    float* out = (float*)d_out;

    progressive_sample_kernel<<<N * (C / GC), THREADS, 0, stream>>>(
        inp, point, offset, out);
}

// Round 12
// 84.228 us; speedup vs baseline: 1.7418x; 1.3505x over previous
//
#include <hip/hip_runtime.h>

// Problem constants (match reference)
constexpr int N = 64, C = 256, H = 64, W = 64, P = 1024;
constexpr int PLANE   = H * W;    // 4096 floats = 16 KB
constexpr int THREADS = 1024;     // 16 waves; 1 gll (1 KB) per wave per plane
constexpr int NBUF    = 4;        // ring of 4 planes, distance-3 prefetch
constexpr int PHASES  = 32;       // 4 tasks x 8 planes, ONE continuous pipeline

typedef float v4f __attribute__((ext_vector_type(4)));

// PERSISTENT NEVER-DRAIN PIPELINE (vs R9's 8 block-generations per CU, each
// paying coord-latency + 3-deep fill + vmcnt(0) drain with the stream dead):
//  - grid 512 = 2 blocks/CU, ALL resident, one generation.
//  - block owns (image n, 32 contiguous channels) = 32 planes staged as one
//    continuous ring; ctx computed ONCE (all tasks share the point set).
//  - per-task stores interleaved mid-pipeline; static vmcnt ledger keeps the
//    prefetch stream alive across task boundaries:
//    queue at top of phase m holds stages {m,m+1,m+2} (+2 store-acks for the
//    3 phases after a task store-pair) -> W(m)=4 for m>=8 && (m&7)<=2,
//    W=2 steady, W=1/0 only in the final two phases.
//  - buffer reuse: phase m issues stage m+3 into buf[(m+3)&3]=buf[(m-1)&3];
//    plane m-1 readers lgkm-drained end of phase m-1, ordered by the top-of-m
//    s_barrier (raw barrier: does NOT touch vmcnt).
__device__ __forceinline__ void stage_plane(const float* __restrict__ src,
                                            float* __restrict__ dst, int t) {
    const int tb = t & ~63;            // wave-uniform LDS base (linear dest)
    __builtin_amdgcn_global_load_lds(
        (const __attribute__((address_space(1))) void*)(src + (t << 2)),
        (__attribute__((address_space(3))) void*)(dst + (tb << 2)),
        16, 0, 0);
}

__global__ __launch_bounds__(THREADS, 8) void progressive_sample_kernel(
    const float* __restrict__ inp,     // [N,C,H,W]
    const float* __restrict__ point,   // [N,P,2] (y,x)
    const float* __restrict__ offset,  // [N,P,2]
    float* __restrict__ out)           // [N,P,C]
{
    __shared__ __align__(16) float buf[NBUF][PLANE];   // 64 KB -> 2 blocks/CU

    const int b    = blockIdx.x;       // 0..511
    const int n    = b >> 3;           // image
    const int setg = b & 7;            // which 32-channel strip
    const int t    = threadIdx.x;      // thread owns point t for ALL tasks
    const int cb   = setg << 5;        // channel base (32 contiguous channels)

    const float* src = inp + ((size_t)n * C + cb) * PLANE;   // planes 0..31

    // --- prologue: coords, then 3 stages in flight, then ctx (no loads) ---
    const float2 pt2 = ((const float2*)point )[((size_t)n << 10) + t];
    const float2 of2 = ((const float2*)offset)[((size_t)n << 10) + t];
    stage_plane(src,             buf[0], t);
    stage_plane(src + PLANE,     buf[1], t);
    stage_plane(src + 2 * PLANE, buf[2], t);

    // ctx once per block (consuming coords auto-waits them; they are oldest
    // in the vm queue, so the 3 stage loads stay in flight)
    const float y = pt2.x + of2.x;
    const float x = pt2.y + of2.y;
    const float y0f = floorf(y), x0f = floorf(x);
    const float ly = y - y0f, lx = x - x0f;
    const float hy = 1.0f - ly, hx = 1.0f - lx;
    const int y0 = (int)y0f, xi0 = (int)x0f, y1 = y0 + 1, xi1 = xi0 + 1;
    const bool vy0 = (unsigned)y0 < (unsigned)H, vy1 = (unsigned)y1 < (unsigned)H;
    const bool vx0 = (unsigned)xi0 < (unsigned)W, vx1 = (unsigned)xi1 < (unsigned)W;
    const int yc0 = min(max(y0, 0), H - 1), yc1 = min(max(y1, 0), H - 1);
    const int xc0 = min(max(xi0, 0), W - 1), xc1 = min(max(xi1, 0), W - 1);
    const int i00 = yc0 * W + xc0, i01 = yc0 * W + xc1;
    const int i10 = yc1 * W + xc0, i11 = yc1 * W + xc1;
    const float w00 = (vy0 && vx0) ? hy * hx : 0.0f;
    const float w01 = (vy0 && vx1) ? hy * lx : 0.0f;
    const float w10 = (vy1 && vx0) ? ly * hx : 0.0f;
    const float w11 = (vy1 && vx1) ? ly * lx : 0.0f;

    float* const obase = out + (((size_t)n << 10) + t) * C + cb;

    float acc[8];                      // statically indexed -> registers

    #pragma unroll
    for (int m = 0; m < PHASES; ++m) {
        // static vmcnt ledger (see header comment)
        const int Wm = (m >= 8 && (m & 7) <= 2) ? 4
                     : (m == PHASES - 2) ? 1
                     : (m == PHASES - 1) ? 0 : 2;
        if (Wm == 4)      asm volatile("s_waitcnt vmcnt(4)" ::: "memory");
        else if (Wm == 2) asm volatile("s_waitcnt vmcnt(2)" ::: "memory");
        else if (Wm == 1) asm volatile("s_waitcnt vmcnt(1)" ::: "memory");
        else              asm volatile("s_waitcnt vmcnt(0)" ::: "memory");
        __builtin_amdgcn_sched_barrier(0);
        __builtin_amdgcn_s_barrier();  // stage(m) visible block-wide;
                                       // plane-(m-1) readers all drained
        __builtin_amdgcn_sched_barrier(0);

        if (m + 3 < PHASES)            // continuous distance-3 prefetch
            stage_plane(src + (size_t)(m + 3) * PLANE, buf[(m + 3) & 3], t);

        const float* __restrict__ bk = buf[m & 3];
        acc[m & 7] = bk[i00] * w00 + bk[i01] * w01
                   + bk[i10] * w10 + bk[i11] * w11;

        asm volatile("s_waitcnt lgkmcnt(0)" ::: "memory");   // my reads done
        __builtin_amdgcn_sched_barrier(0);

        if ((m & 7) == 7) {            // task epilogue: 32 B of the point's
                                       // line (plain cached stores; L2 merges)
            float* o = obase + ((m >> 3) << 3);
            v4f lo = { acc[0], acc[1], acc[2], acc[3] };
            v4f hi = { acc[4], acc[5], acc[6], acc[7] };
            *(v4f*)o       = lo;
            *(v4f*)(o + 4) = hi;
        }
    }
}

extern "C" void kernel_launch(void* const* d_in, const int* in_sizes, int n_in,
                              void* d_out, int out_size, void* d_ws, size_t ws_size,
                              hipStream_t stream) {
    const float* inp    = (const float*)d_in[0];
    const float* point  = (const float*)d_in[1];
    const float* offset = (const float*)d_in[2];
    float* out = (float*)d_out;

    progressive_sample_kernel<<<N * 8, THREADS, 0, stream>>>(
        inp, point, offset, out);
}